// Round 1
// baseline (341.252 us; speedup 1.0000x reference)
//
#include <hip/hip_runtime.h>
#include <hip/hip_fp16.h>

// ---------------------------------------------------------------------------
// DeterministicLSTMSensorBasedForwardDynamics on MI355X (gfx950) — round 9
//
// Round-8 post-mortem: 261-265 us, MfmaUtil 25%, VALUBusy 31%, ~45% stall.
// lds_barrier (keeping stream loads in flight across barriers) was ~null vs
// r6 -> we are NOT hard against the L2 port; the stall is serialization:
// the interleaved K-loop waits on ring refills with nothing else to issue,
// then the whole cell update (serial sigmoid chains) runs as a dead tail
// before the barrier.
//
// Round 9 = PHASE-SPLIT step (single theme, everything else identical):
//   phase 1: all 44 cb0 MFMAs (operands 100% resident: rw AGPRs, Wc LDS,
//            ring slots 0..3 prefetched last step) -> full-rate MFMA burst
//            right after the barrier while the ring refills underneath.
//   cb0 cell update between phases -> its VALU/trans overlaps phase-2
//            stream waits instead of serializing at the end.
//   phase 2: 44 streamed cb1 MFMAs, uniform ring refills (kt10 special case
//            gone; stream order = [cb0kt10 g0..3][cb1 kt*g], 48%8==0 holds).
//   acc0/acc1 no longer co-live -> ~16 fewer peak regs (away from the r7
//            spill cliff). Cost: a-frags re-read in phase 2 (+11 ds_read_b128
//            /wave/step on the non-critical LDS conveyor).
// Prediction: dur -> ~215-235 us, MfmaUtil ~29%, bank-conflicts +40%,
// VGPR <= 124, WRITE_SIZE ~1 MB (spill guard). Null result => L2-delivery
// bound => next lever is fp8 streamed weights.
// ---------------------------------------------------------------------------

typedef _Float16 h8 __attribute__((ext_vector_type(8)));
typedef _Float16 hv4 __attribute__((ext_vector_type(4)));
typedef float f4 __attribute__((ext_vector_type(4)));

#define NB    4096
#define TSEQ  50
#define DOBS  64
#define DACT  16
#define HD    256
#define DOUT  64
#define NL    5

#define NKT   11        // K-tiles of 32 covering 352 = 80 (x) + 256 (h) + 16 pad
#define AROW  360       // LDS A-row stride in halves
#define MTILE 16
#define NWG   (NB / MTILE)   // 256
#define NTHR  512            // 8 waves

// ws layout in halves (written by repack_kernel)
#define WS_MLP   (704 * 512)
#define WS_WOUT  (WS_MLP + 640 * 512)

// LDS layout (halves): As0 | As1 | Wcache(8 waves x WCB blocks)
#define LDS_AS     (MTILE * AROW)      // 5760 per panel
#define LDS_WCOFF  (2 * LDS_AS)        // 11520
#define WCB        16                  // LDS-resident blocks per wave (cb0 kt6..9)
#define LDS_HALVES (LDS_WCOFF + 8 * WCB * 512)   // 77056
#define LDS_BYTES  (LDS_HALVES * 2)              // 154112  (<= 160 KiB)
static_assert(LDS_BYTES <= 160 * 1024, "LDS overflow");

// streaming: positions 0..3 = cb0 kt10 (consumed end of phase 1),
// positions 4..47 = cb1 kt0..10 x g (consumed in phase 2).
// 48 % 8 == 0 -> the 8-slot ring persists ACROSS steps (last 8 refills of a
// step prime the next step's positions 0..7).
#define SB_P     8
#define NSTREAM  48

// Barrier that does NOT drain vmcnt: cross-wave data dependencies at the
// t-loop barrier are ds_write-only (h and x panels), covered by lgkmcnt(0).
// In-flight global loads (stream ring, x prefetch) target private VGPRs and
// are synchronized by their own vmcnt-before-use waits -> legal to keep
// flying across s_barrier.
__device__ __forceinline__ void lds_barrier() {
  asm volatile("s_waitcnt lgkmcnt(0)\n\ts_barrier" ::: "memory");
}

// sigmoid via native v_exp_f32 + v_rcp_f32 (1-ulp; fp16 weights dominate err).
__device__ __forceinline__ float sigf(float x) {
  const float e = __builtin_amdgcn_exp2f(x * -1.44269504088896f);
  return __builtin_amdgcn_rcpf(1.f + e);
}

// stream position c -> block offset (halves) rel. to wave base (w*2*NKT*512):
//   c in [0,4):   cb0 kt10, g = c        -> ((g*16+0)*NKT + 10)*512
//   c in [4,48):  cb1, kt=(c-4)>>2, g=(c-4)&3 -> ((g*16+1)*NKT + kt)*512
__device__ constexpr int soff(int c) {
  if (c < 4) { return ((c * 16) * NKT + 10) * 512; }
  const int g = (c - 4) & 3, kt = (c - 4) >> 2;
  return ((g * 16 + 1) * NKT + kt) * 512;
}

// --------------------------- weight repack ---------------------------------
__global__ void __launch_bounds__(256) repack_kernel(
    const float* __restrict__ Wi, const float* __restrict__ Wh,
    const float* __restrict__ mlpW, const float* __restrict__ Wout,
    _Float16* __restrict__ wsW)
{
  const int gt  = blockIdx.x * 256 + threadIdx.x;
  const int gb  = gt >> 6;
  const int l   = gt & 63;
  const int l15 = l & 15;
  const int kb  = (l >> 4) * 8;
  h8 v;
  if (gb < 704) {                       // LSTM: Wcat[k][n], k<80 -> Wi, k<336 -> Wh, else 0
    const int nt = gb / NKT, kt = gb - nt * NKT;
    const int n  = nt * 16 + l15;
#pragma unroll
    for (int j = 0; j < 8; ++j) {
      const int k = kt * 32 + kb + j;
      float s = 0.f;
      if (k < 80)       s = Wi[k * 1024 + n];
      else if (k < 336) s = Wh[(k - 80) * 1024 + n];
      v[j] = (_Float16)s;
    }
  } else if (gb < 1344) {               // MLP layer weights [5][256][256]
    const int b2 = gb - 704;
    const int L  = b2 >> 7, rr = b2 & 127;
    const int nt = rr >> 3, kt = rr & 7;
    const int n  = nt * 16 + l15;
#pragma unroll
    for (int j = 0; j < 8; ++j) {
      const int k = kt * 32 + kb + j;
      v[j] = (_Float16)mlpW[(size_t)L * 65536 + k * 256 + n];
    }
  } else {                              // Wout [256][64]
    const int b3 = gb - 1344;
    const int nt = b3 >> 3, kt = b3 & 7;
    const int n  = nt * 16 + l15;
#pragma unroll
    for (int j = 0; j < 8; ++j) {
      const int k = kt * 32 + kb + j;
      v[j] = (_Float16)Wout[k * 64 + n];
    }
  }
  *(h8*)&wsW[(size_t)gb * 512 + l * 8] = v;
}

// ------------------------------ main kernel --------------------------------
__global__ void __launch_bounds__(NTHR, 2) lstm_kernel(
    const float* __restrict__ traj, const float* __restrict__ acts,
    const float* __restrict__ bh,   const float* __restrict__ mlpb,
    const float* __restrict__ bout, const _Float16* __restrict__ wsW,
    float* __restrict__ out)
{
  extern __shared__ __align__(16) _Float16 lds[];
  _Float16* As0 = lds;
  _Float16* As1 = lds + LDS_AS;
  _Float16* Wc  = lds + LDS_WCOFF;

  const int tid = threadIdx.x;
  const int w   = tid >> 6;        // wave 0..7: owns h-cols [32w, 32w+32)
  const int l   = tid & 63;
  const int l15 = l & 15;
  const int lq  = l >> 4;
  const int rbase = blockIdx.x * MTILE;

  // Zero both A panels (h starts 0; pad cols 336..359 stay 0 forever).
  for (int i = tid; i < 2 * LDS_AS; i += NTHR) lds[i] = (_Float16)0.f;

  // LDS-resident: 16 blocks/wave = (cb0, kt6..9, g0..3)
#pragma unroll
  for (int j = 0; j < WCB; ++j) {
    const int g = j & 3, kt = 6 + (j >> 2);
    const h8 v = *(const h8*)&wsW[(size_t)((g * 16 + w * 2) * NKT + kt) * 512 + l * 8];
    *(h8*)&Wc[(w * WCB + j) * 512 + l * 8] = v;
  }

  // Register-resident: 24 blocks/wave = (cb0, kt0..5, g0..3) — AGPR-backed.
  h8 rw[24];
#pragma unroll
  for (int kt = 0; kt < 6; ++kt)
#pragma unroll
    for (int g = 0; g < 4; ++g)
      rw[kt * 4 + g] = *(const h8*)&wsW[(size_t)((g * 16 + w * 2) * NKT + kt) * 512 + l * 8];

  // Persistent cell state + biases
  float c[2][4];
#pragma unroll
  for (int cb = 0; cb < 2; ++cb)
#pragma unroll
    for (int r = 0; r < 4; ++r) c[cb][r] = 0.f;

  float bias[4][2];
#pragma unroll
  for (int g = 0; g < 4; ++g) {
    bias[g][0] = bh[g * 256 + w * 32 + l15];
    bias[g][1] = bh[g * 256 + w * 32 + 16 + l15];
  }

  __syncthreads();

  // Stage x_0 into As0 cols 0..79 (traj via waves 0-3, acts via waves 4-7)
  if (tid < 256) {
    const int r = tid >> 4, q = tid & 15;
    const float4 v = *(const float4*)&traj[(size_t)(rbase + r) * (TSEQ * DOBS) + q * 4];
    hv4 hx = { (_Float16)v.x, (_Float16)v.y, (_Float16)v.z, (_Float16)v.w };
    *(hv4*)&As0[r * AROW + q * 4] = hx;
  } else {
    const int r = (tid - 256) >> 4, q = (tid - 256) & 15;
    As0[r * AROW + 64 + q] = (_Float16)acts[(size_t)(rbase + r) * (TSEQ * DACT) + q];
  }
  __syncthreads();

  unsigned long long wbits = (unsigned long long)(const void*)wsW;

  // Persistent 8-slot stream ring. Primed once here; thereafter each step's
  // last 8 refills prime the next step (stream order periodic mod 48).
  h8 sb[SB_P];
  {
    const _Float16* wlb0 = wsW + (size_t)(w * 2 * NKT) * 512 + l * 8;
#pragma unroll
    for (int cc = 0; cc < SB_P; ++cc) sb[cc] = *(const h8*)&wlb0[soff(cc)];
  }

  auto step = [&](int t, const _Float16* buf, _Float16* nbuf) {
    // Memory clobber: stream loads can't be hoisted/CSE'd across steps and
    // rw[] can't be legally rematerialized from wsW.
    asm volatile("" : "+s"(wbits) : : "memory");
    const _Float16* wst = (const _Float16*)wbits;
    const _Float16* wlb = wst + (size_t)(w * 2 * NKT) * 512 + l * 8;

    // x(t+1): load to registers now, store to LDS at end of step.
    float4 xv; float xa;
    const bool havex = (t + 1 < TSEQ);
    if (havex) {
      if (tid < 256) {
        const int r = tid >> 4, q = tid & 15;
        xv = *(const float4*)&traj[(size_t)(rbase + r) * (TSEQ * DOBS) + (t + 1) * DOBS + q * 4];
      } else {
        const int r = (tid - 256) >> 4, q = (tid - 256) & 15;
        xa = acts[(size_t)(rbase + r) * (TSEQ * DACT) + (t + 1) * DACT + q];
      }
    }

    // ---------------- phase 1: cb0 — fully on-chip/prefetched --------------
    // rw (kt0..5, AGPR), Wc (kt6..9, LDS), ring slots 0..3 (kt10, prefetched
    // last step). Zero stream dependence -> full-rate MFMA burst right after
    // the barrier; phase-2 refills start flowing underneath.
    f4 acc0[4];
#pragma unroll
    for (int g = 0; g < 4; ++g) acc0[g] = f4{0.f, 0.f, 0.f, 0.f};

#pragma unroll
    for (int kt = 0; kt < NKT; ++kt) {
      const h8 a0 = *(const h8*)&buf[l15 * AROW + kt * 32 + lq * 8];
#pragma unroll
      for (int g = 0; g < 4; ++g) {
        h8 bf0;
        if (kt < 6)       bf0 = rw[kt * 4 + g];
        else if (kt < 10) bf0 = *(const h8*)&Wc[(w * WCB + (kt - 6) * 4 + g) * 512 + l * 8];
        else              bf0 = sb[g];                       // position g
        acc0[g] = __builtin_amdgcn_mfma_f32_16x16x32_f16(a0, bf0, acc0[g], 0, 0, 0);
        if (kt == 10) sb[g] = *(const h8*)&wlb[soff(8 + g)]; // refill pos 8+g
      }
    }

    // ---------------- cb0 cell update (overlaps phase-2 stream fill) -------
    {
      const int colh = 80 + w * 32 + l15;   // cb=0
#pragma unroll
      for (int r = 0; r < 4; ++r) {
        const float zi = acc0[0][r] + bias[0][0];
        const float zf = acc0[1][r] + bias[1][0];
        const float zg = acc0[2][r] + bias[2][0];
        const float zo = acc0[3][r] + bias[3][0];
        const float ig = sigf(zi), fg = sigf(zf), og = sigf(zo);
        const float gg = zg * sigf(zg);
        const float cn = fg * c[0][r] + ig * gg;
        c[0][r] = cn;
        nbuf[(lq * 4 + r) * AROW + colh] = (_Float16)(og * cn * sigf(cn));
      }
    }

    // ---------------- phase 2: cb1 — streamed through the ring -------------
    // position c = 4 + kt*4 + g, slot c&7; refill with (c+8)%48 (the last 8
    // refills fetch NEXT step's positions 0..7).
    f4 acc1[4];
#pragma unroll
    for (int g = 0; g < 4; ++g) acc1[g] = f4{0.f, 0.f, 0.f, 0.f};

#pragma unroll
    for (int kt = 0; kt < NKT; ++kt) {
      const h8 a1 = *(const h8*)&buf[l15 * AROW + kt * 32 + lq * 8];
#pragma unroll
      for (int g = 0; g < 4; ++g) {
        const int cc = 4 + kt * 4 + g;
        acc1[g] = __builtin_amdgcn_mfma_f32_16x16x32_f16(a1, sb[cc & 7], acc1[g], 0, 0, 0);
        sb[cc & 7] = *(const h8*)&wlb[soff((cc + SB_P) % NSTREAM)];
      }
    }

    // ---------------- cb1 cell update --------------------------------------
    {
      const int colh = 80 + w * 32 + 16 + l15;   // cb=1
#pragma unroll
      for (int r = 0; r < 4; ++r) {
        const float zi = acc1[0][r] + bias[0][1];
        const float zf = acc1[1][r] + bias[1][1];
        const float zg = acc1[2][r] + bias[2][1];
        const float zo = acc1[3][r] + bias[3][1];
        const float ig = sigf(zi), fg = sigf(zf), og = sigf(zo);
        const float gg = zg * sigf(zg);
        const float cn = fg * c[1][r] + ig * gg;
        c[1][r] = cn;
        nbuf[(lq * 4 + r) * AROW + colh] = (_Float16)(og * cn * sigf(cn));
      }
    }

    // Deferred x(t+1) store into nbuf cols 0..79.
    if (havex) {
      if (tid < 256) {
        const int r = tid >> 4, q = tid & 15;
        hv4 hx = { (_Float16)xv.x, (_Float16)xv.y, (_Float16)xv.z, (_Float16)xv.w };
        *(hv4*)&nbuf[r * AROW + q * 4] = hx;
      } else {
        const int r = (tid - 256) >> 4, q = (tid - 256) & 15;
        nbuf[r * AROW + 64 + q] = (_Float16)xa;
      }
    }
  };

#pragma unroll 1
  for (int t = 0; t < TSEQ; t += 2) {
    step(t, As0, As1);
    lds_barrier();           // LDS-only: stream ring stays in flight
    step(t + 1, As1, As0);
    lds_barrier();
  }

  // ---------------- MLP head ----------------
  // Final h in As0 cols 80..335. Move to As1 cols 0..255.
  for (int i = tid; i < MTILE * HD; i += NTHR) {
    const int r = i >> 8, cc = i & 255;
    As1[r * AROW + cc] = As0[r * AROW + 80 + cc];
  }
  __syncthreads();

#pragma unroll 1
  for (int L = 0; L < NL; ++L) {
    const _Float16* in = (L & 1) ? As0 : As1;
    _Float16*       ob = (L & 1) ? As1 : As0;
    const _Float16* wl = wsW + WS_MLP + (size_t)L * (128 * 512);
    float bcol[2];
    bcol[0] = mlpb[L * HD + w * 32 + l15];
    bcol[1] = mlpb[L * HD + w * 32 + 16 + l15];

    f4 acc[2];
    acc[0] = f4{0.f, 0.f, 0.f, 0.f};
    acc[1] = f4{0.f, 0.f, 0.f, 0.f};
#pragma unroll
    for (int kt = 0; kt < 8; ++kt) {
      const h8 a0 = *(const h8*)&in[l15 * AROW + kt * 32 + lq * 8];
#pragma unroll
      for (int cb = 0; cb < 2; ++cb) {
        const h8 bf = *(const h8*)&wl[(size_t)((w * 2 + cb) * 8 + kt) * 512 + l * 8];
        acc[cb] = __builtin_amdgcn_mfma_f32_16x16x32_f16(a0, bf, acc[cb], 0, 0, 0);
      }
    }
#pragma unroll
    for (int cb = 0; cb < 2; ++cb)
#pragma unroll
      for (int r = 0; r < 4; ++r) {
        const float z = acc[cb][r] + bcol[cb];
        ob[(lq * 4 + r) * AROW + w * 32 + cb * 16 + l15] = (_Float16)(z * sigf(z));
      }
    __syncthreads();
  }

  // Output layer: final activations in As0 (NL=5 odd). N=64 -> waves 0..3.
  if (w < 4) {
    const _Float16* wo = wsW + WS_WOUT;
    const float bo = bout[w * 16 + l15];
    f4 acc0 = f4{0.f, 0.f, 0.f, 0.f};
#pragma unroll
    for (int kt = 0; kt < 8; ++kt) {
      const h8 a0 = *(const h8*)&As0[l15 * AROW + kt * 32 + lq * 8];
      const h8 bf = *(const h8*)&wo[(size_t)(w * 8 + kt) * 512 + l * 8];
      acc0 = __builtin_amdgcn_mfma_f32_16x16x32_f16(a0, bf, acc0, 0, 0, 0);
    }
#pragma unroll
    for (int r = 0; r < 4; ++r)
      out[(size_t)(rbase + lq * 4 + r) * DOUT + w * 16 + l15] = acc0[r] + bo;
  }
}

// ------------------------------- launcher ----------------------------------
extern "C" void kernel_launch(void* const* d_in, const int* in_sizes, int n_in,
                              void* d_out, int out_size, void* d_ws, size_t ws_size,
                              hipStream_t stream)
{
  const float* traj = (const float*)d_in[0];
  const float* acts = (const float*)d_in[1];
  const float* Wi   = (const float*)d_in[2];
  const float* Wh   = (const float*)d_in[3];
  const float* bh   = (const float*)d_in[4];
  const float* mlpW = (const float*)d_in[5];
  const float* mlpb = (const float*)d_in[6];
  const float* Wout = (const float*)d_in[7];
  const float* bout = (const float*)d_in[8];
  _Float16* wsW = (_Float16*)d_ws;   // needs 1,409,024 bytes of workspace

  (void)hipFuncSetAttribute((const void*)lstm_kernel,
                            hipFuncAttributeMaxDynamicSharedMemorySize, LDS_BYTES);

  repack_kernel<<<344, 256, 0, stream>>>(Wi, Wh, mlpW, Wout, wsW);
  lstm_kernel<<<NWG, NTHR, LDS_BYTES, stream>>>(traj, acts, bh, mlpb, bout, wsW, (float*)d_out);
}

// Round 3
// 334.979 us; speedup vs baseline: 1.0187x; 1.0187x over previous
//
#include <hip/hip_runtime.h>
#include <hip/hip_fp16.h>

// ---------------------------------------------------------------------------
// DeterministicLSTMSensorBasedForwardDynamics on MI355X (gfx950) — round 11
// (= round 10 resubmitted verbatim: the r10 bench died in container acquire,
//  no kernel data was collected. Audit of ring algebra found no hazards.)
//
// Round-9 post-mortem: phase-split REGRESSED 261->290 us. Mechanism: in the
// interleaved r8 loop, a ring slot refilled at stream position cc is consumed
// at cc+8 with positions advancing 4/kt -> 16-MFMA cover; r9's phase 2 had
// only 4 MFMAs/kt -> 8-MFMA cover, i.e. the latency window HALVED (plus the
// a-frag double-read doubled LDS bank conflicts 4.9M->9.4M). The sensitivity
// to the window size is evidence we are (at least partly) L2-LATENCY bound,
// not port-BW bound.
//
// Round 10/11 = r8 interleaved structure restored, with two levers:
//   1. Ring 8 -> 13 slots, funded by rw 24 -> 20 blocks (cb0 kt0..4 in AGPR;
//      cb0-kt5 joins the stream). NSTREAM 48 -> 52, 52 % 13 == 0 so the
//      persistent cross-step ring is preserved. Refill-to-consume cover
//      16 -> ~22 MFMAs (+38%); stream bytes +8.3% (48->52 KB/wave/step).
//      Register fit: arch 124+20=144, AGPR 80+32=112, total 256 (at the
//      2-waves/SIMD wall) -> WRITE_SIZE is the spill tripwire.
//   2. Fused-rcp cell update: i*g and o*silu(c) each share one v_rcp over a
//      product of (1+e^-z) terms -> 10 -> 8 trans per (cb,r), -20% of the
//      ~2.5K cyc/step transcendental term. Same math, reassociated.
// Prediction: dur ~228-240 us, MfmaUtil ~28%, bank conflicts ~4.9M, WRITE
// ~1 MB. WRITE >5 MB -> spill, confounded. Clean null -> L2-port bound ->
// next lever is fp8 streamed weights.
// ---------------------------------------------------------------------------

typedef _Float16 h8 __attribute__((ext_vector_type(8)));
typedef _Float16 hv4 __attribute__((ext_vector_type(4)));
typedef float f4 __attribute__((ext_vector_type(4)));

#define NB    4096
#define TSEQ  50
#define DOBS  64
#define DACT  16
#define HD    256
#define DOUT  64
#define NL    5

#define NKT   11        // K-tiles of 32 covering 352 = 80 (x) + 256 (h) + 16 pad
#define AROW  360       // LDS A-row stride in halves
#define MTILE 16
#define NWG   (NB / MTILE)   // 256
#define NTHR  512            // 8 waves

// ws layout in halves (written by repack_kernel)
#define WS_MLP   (704 * 512)
#define WS_WOUT  (WS_MLP + 640 * 512)

// LDS layout (halves): As0 | As1 | Wcache(8 waves x WCB blocks)
#define LDS_AS     (MTILE * AROW)      // 5760 per panel
#define LDS_WCOFF  (2 * LDS_AS)        // 11520
#define WCB        16                  // LDS-resident blocks per wave (cb0 kt6..9)
#define LDS_HALVES (LDS_WCOFF + 8 * WCB * 512)   // 77056
#define LDS_BYTES  (LDS_HALVES * 2)              // 154112  (<= 160 KiB)
static_assert(LDS_BYTES <= 160 * 1024, "LDS overflow");

// Streaming (consumption order through the interleaved K-loop):
//   c in [0,20):  cb1 kt0..4           (kt=c>>2,        g=c&3)
//   c in [20,24): cb0 kt5              (g=c-20)
//   c in [24,28): cb1 kt5              (g=c-24)
//   c in [28,44): cb1 kt6..9           (kt=6+((c-28)>>2), g=(c-28)&3)
//   c in [44,48): cb0 kt10             (g=c-44)
//   c in [48,52): cb1 kt10             (g=c-48)
// 52 % 13 == 0 -> the 13-slot ring persists ACROSS steps (last 13 refills of
// a step prime the next step's positions 0..12).
#define SB_P     13
#define NSTREAM  52

// Barrier that does NOT drain vmcnt: cross-wave data dependencies at the
// t-loop barrier are ds_write-only (h and x panels), covered by lgkmcnt(0).
// In-flight global loads (stream ring, x prefetch) target private VGPRs and
// are synchronized by their own vmcnt-before-use waits -> legal to keep
// flying across s_barrier.
__device__ __forceinline__ void lds_barrier() {
  asm volatile("s_waitcnt lgkmcnt(0)\n\ts_barrier" ::: "memory");
}

// stream position c -> block offset (halves) rel. to wave base (w*2*NKT*512)
__device__ constexpr int soff(int c) {
  int kt, cbb, g;
  if (c < 20)      { kt = c >> 2;              cbb = 1; g = c & 3; }
  else if (c < 24) { kt = 5;                   cbb = 0; g = c - 20; }
  else if (c < 28) { kt = 5;                   cbb = 1; g = c - 24; }
  else if (c < 44) { kt = 6 + ((c - 28) >> 2); cbb = 1; g = (c - 28) & 3; }
  else if (c < 48) { kt = 10;                  cbb = 0; g = c - 44; }
  else             { kt = 10;                  cbb = 1; g = c - 48; }
  return ((g * 16 + cbb) * NKT + kt) * 512;
}

// --------------------------- weight repack ---------------------------------
__global__ void __launch_bounds__(256) repack_kernel(
    const float* __restrict__ Wi, const float* __restrict__ Wh,
    const float* __restrict__ mlpW, const float* __restrict__ Wout,
    _Float16* __restrict__ wsW)
{
  const int gt  = blockIdx.x * 256 + threadIdx.x;
  const int gb  = gt >> 6;
  const int l   = gt & 63;
  const int l15 = l & 15;
  const int kb  = (l >> 4) * 8;
  h8 v;
  if (gb < 704) {                       // LSTM: Wcat[k][n], k<80 -> Wi, k<336 -> Wh, else 0
    const int nt = gb / NKT, kt = gb - nt * NKT;
    const int n  = nt * 16 + l15;
#pragma unroll
    for (int j = 0; j < 8; ++j) {
      const int k = kt * 32 + kb + j;
      float s = 0.f;
      if (k < 80)       s = Wi[k * 1024 + n];
      else if (k < 336) s = Wh[(k - 80) * 1024 + n];
      v[j] = (_Float16)s;
    }
  } else if (gb < 1344) {               // MLP layer weights [5][256][256]
    const int b2 = gb - 704;
    const int L  = b2 >> 7, rr = b2 & 127;
    const int nt = rr >> 3, kt = rr & 7;
    const int n  = nt * 16 + l15;
#pragma unroll
    for (int j = 0; j < 8; ++j) {
      const int k = kt * 32 + kb + j;
      v[j] = (_Float16)mlpW[(size_t)L * 65536 + k * 256 + n];
    }
  } else {                              // Wout [256][64]
    const int b3 = gb - 1344;
    const int nt = b3 >> 3, kt = b3 & 7;
    const int n  = nt * 16 + l15;
#pragma unroll
    for (int j = 0; j < 8; ++j) {
      const int k = kt * 32 + kb + j;
      v[j] = (_Float16)Wout[k * 64 + n];
    }
  }
  *(h8*)&wsW[(size_t)gb * 512 + l * 8] = v;
}

// ------------------------------ main kernel --------------------------------
__global__ void __launch_bounds__(NTHR, 2) lstm_kernel(
    const float* __restrict__ traj, const float* __restrict__ acts,
    const float* __restrict__ bh,   const float* __restrict__ mlpb,
    const float* __restrict__ bout, const _Float16* __restrict__ wsW,
    float* __restrict__ out)
{
  extern __shared__ __align__(16) _Float16 lds[];
  _Float16* As0 = lds;
  _Float16* As1 = lds + LDS_AS;
  _Float16* Wc  = lds + LDS_WCOFF;

  const int tid = threadIdx.x;
  const int w   = tid >> 6;        // wave 0..7: owns h-cols [32w, 32w+32)
  const int l   = tid & 63;
  const int l15 = l & 15;
  const int lq  = l >> 4;
  const int rbase = blockIdx.x * MTILE;

  // Zero both A panels (h starts 0; pad cols 336..359 stay 0 forever).
  for (int i = tid; i < 2 * LDS_AS; i += NTHR) lds[i] = (_Float16)0.f;

  // LDS-resident: 16 blocks/wave = (cb0, kt6..9, g0..3)
#pragma unroll
  for (int j = 0; j < WCB; ++j) {
    const int g = j & 3, kt = 6 + (j >> 2);
    const h8 v = *(const h8*)&wsW[(size_t)((g * 16 + w * 2) * NKT + kt) * 512 + l * 8];
    *(h8*)&Wc[(w * WCB + j) * 512 + l * 8] = v;
  }

  // Register-resident: 20 blocks/wave = (cb0, kt0..4, g0..3) — AGPR-backed.
  h8 rw[20];
#pragma unroll
  for (int kt = 0; kt < 5; ++kt)
#pragma unroll
    for (int g = 0; g < 4; ++g)
      rw[kt * 4 + g] = *(const h8*)&wsW[(size_t)((g * 16 + w * 2) * NKT + kt) * 512 + l * 8];

  // Persistent cell state + biases
  float c[2][4];
#pragma unroll
  for (int cb = 0; cb < 2; ++cb)
#pragma unroll
    for (int r = 0; r < 4; ++r) c[cb][r] = 0.f;

  float bias[4][2];
#pragma unroll
  for (int g = 0; g < 4; ++g) {
    bias[g][0] = bh[g * 256 + w * 32 + l15];
    bias[g][1] = bh[g * 256 + w * 32 + 16 + l15];
  }

  __syncthreads();

  // Stage x_0 into As0 cols 0..79 (traj via waves 0-3, acts via waves 4-7)
  if (tid < 256) {
    const int r = tid >> 4, q = tid & 15;
    const float4 v = *(const float4*)&traj[(size_t)(rbase + r) * (TSEQ * DOBS) + q * 4];
    hv4 hx = { (_Float16)v.x, (_Float16)v.y, (_Float16)v.z, (_Float16)v.w };
    *(hv4*)&As0[r * AROW + q * 4] = hx;
  } else {
    const int r = (tid - 256) >> 4, q = (tid - 256) & 15;
    As0[r * AROW + 64 + q] = (_Float16)acts[(size_t)(rbase + r) * (TSEQ * DACT) + q];
  }
  __syncthreads();

  unsigned long long wbits = (unsigned long long)(const void*)wsW;

  // Persistent 13-slot stream ring. Primed once here; thereafter each step's
  // last 13 refills prime the next step (stream order periodic mod 52).
  h8 sb[SB_P];
  {
    const _Float16* wlb0 = wsW + (size_t)(w * 2 * NKT) * 512 + l * 8;
#pragma unroll
    for (int cc = 0; cc < SB_P; ++cc) sb[cc] = *(const h8*)&wlb0[soff(cc)];
  }

  auto step = [&](int t, const _Float16* buf, _Float16* nbuf) {
    // Memory clobber: stream loads can't be hoisted/CSE'd across steps and
    // rw[] can't be legally rematerialized from wsW.
    asm volatile("" : "+s"(wbits) : : "memory");
    const _Float16* wst = (const _Float16*)wbits;
    const _Float16* wlb = wst + (size_t)(w * 2 * NKT) * 512 + l * 8;

    // x(t+1): load to registers now, store to LDS at end of step.
    float4 xv; float xa;
    const bool havex = (t + 1 < TSEQ);
    if (havex) {
      if (tid < 256) {
        const int r = tid >> 4, q = tid & 15;
        xv = *(const float4*)&traj[(size_t)(rbase + r) * (TSEQ * DOBS) + (t + 1) * DOBS + q * 4];
      } else {
        const int r = (tid - 256) >> 4, q = (tid - 256) & 15;
        xa = acts[(size_t)(rbase + r) * (TSEQ * DACT) + (t + 1) * DACT + q];
      }
    }

    // ---------------- fused K-loop: cb0 (mostly on-chip) + cb1 (streamed) --
    f4 acc0[4], acc1[4];
#pragma unroll
    for (int g = 0; g < 4; ++g) {
      acc0[g] = f4{0.f, 0.f, 0.f, 0.f};
      acc1[g] = f4{0.f, 0.f, 0.f, 0.f};
    }

#pragma unroll
    for (int kt = 0; kt < NKT; ++kt) {
      const h8 a0 = *(const h8*)&buf[l15 * AROW + kt * 32 + lq * 8];
#pragma unroll
      for (int g = 0; g < 4; ++g) {
        // cb0 fragment: registers (kt<5), LDS cache (kt6..9), stream (kt5,
        // kt10). Streamed slots refill immediately with position c+13.
        if (kt < 5) {
          acc0[g] = __builtin_amdgcn_mfma_f32_16x16x32_f16(a0, rw[kt * 4 + g], acc0[g], 0, 0, 0);
        } else if (kt >= 6 && kt <= 9) {
          const h8 bf0 = *(const h8*)&Wc[(w * WCB + (kt - 6) * 4 + g) * 512 + l * 8];
          acc0[g] = __builtin_amdgcn_mfma_f32_16x16x32_f16(a0, bf0, acc0[g], 0, 0, 0);
        } else {
          const int c0 = (kt == 5) ? (20 + g) : (44 + g);
          acc0[g] = __builtin_amdgcn_mfma_f32_16x16x32_f16(a0, sb[c0 % SB_P], acc0[g], 0, 0, 0);
          sb[c0 % SB_P] = *(const h8*)&wlb[soff((c0 + SB_P) % NSTREAM)];
        }

        // cb1 fragment: streamed every kt; position advances 4/kt (8 at kt5
        // and kt10), giving ~22-MFMA refill-to-consume cover.
        const int c1 = kt * 4 + g + (kt >= 5 ? 4 : 0) + (kt >= 10 ? 4 : 0);
        acc1[g] = __builtin_amdgcn_mfma_f32_16x16x32_f16(a0, sb[c1 % SB_P], acc1[g], 0, 0, 0);
        sb[c1 % SB_P] = *(const h8*)&wlb[soff((c1 + SB_P) % NSTREAM)];
      }
    }

    // ---------------- cell update (fused-rcp: 5 exp + 3 rcp per (cb,r)) ----
    const float KE = -1.44269504088896f;   // -log2(e)
    {
      const int colh = 80 + w * 32 + l15;   // cb=0
#pragma unroll
      for (int r = 0; r < 4; ++r) {
        const float zi = acc0[0][r] + bias[0][0];
        const float zf = acc0[1][r] + bias[1][0];
        const float zg = acc0[2][r] + bias[2][0];
        const float zo = acc0[3][r] + bias[3][0];
        const float ei = __builtin_amdgcn_exp2f(zi * KE);
        const float ef = __builtin_amdgcn_exp2f(zf * KE);
        const float eg = __builtin_amdgcn_exp2f(zg * KE);
        const float eo = __builtin_amdgcn_exp2f(zo * KE);
        const float fg = __builtin_amdgcn_rcpf(1.f + ef);
        const float igg = zg * __builtin_amdgcn_rcpf((1.f + ei) * (1.f + eg)); // i*g
        const float cn = fg * c[0][r] + igg;
        c[0][r] = cn;
        const float ec = __builtin_amdgcn_exp2f(cn * KE);
        const float hn = cn * __builtin_amdgcn_rcpf((1.f + eo) * (1.f + ec)); // o*silu(c)
        nbuf[(lq * 4 + r) * AROW + colh] = (_Float16)hn;
      }
    }
    {
      const int colh = 80 + w * 32 + 16 + l15;   // cb=1
#pragma unroll
      for (int r = 0; r < 4; ++r) {
        const float zi = acc1[0][r] + bias[0][1];
        const float zf = acc1[1][r] + bias[1][1];
        const float zg = acc1[2][r] + bias[2][1];
        const float zo = acc1[3][r] + bias[3][1];
        const float ei = __builtin_amdgcn_exp2f(zi * KE);
        const float ef = __builtin_amdgcn_exp2f(zf * KE);
        const float eg = __builtin_amdgcn_exp2f(zg * KE);
        const float eo = __builtin_amdgcn_exp2f(zo * KE);
        const float fg = __builtin_amdgcn_rcpf(1.f + ef);
        const float igg = zg * __builtin_amdgcn_rcpf((1.f + ei) * (1.f + eg));
        const float cn = fg * c[1][r] + igg;
        c[1][r] = cn;
        const float ec = __builtin_amdgcn_exp2f(cn * KE);
        const float hn = cn * __builtin_amdgcn_rcpf((1.f + eo) * (1.f + ec));
        nbuf[(lq * 4 + r) * AROW + colh] = (_Float16)hn;
      }
    }

    // Deferred x(t+1) store into nbuf cols 0..79.
    if (havex) {
      if (tid < 256) {
        const int r = tid >> 4, q = tid & 15;
        hv4 hx = { (_Float16)xv.x, (_Float16)xv.y, (_Float16)xv.z, (_Float16)xv.w };
        *(hv4*)&nbuf[r * AROW + q * 4] = hx;
      } else {
        const int r = (tid - 256) >> 4, q = (tid - 256) & 15;
        nbuf[r * AROW + 64 + q] = (_Float16)xa;
      }
    }
  };

#pragma unroll 1
  for (int t = 0; t < TSEQ; t += 2) {
    step(t, As0, As1);
    lds_barrier();           // LDS-only: stream ring stays in flight
    step(t + 1, As1, As0);
    lds_barrier();
  }

  // ---------------- MLP head ----------------
  // Final h in As0 cols 80..335. Move to As1 cols 0..255.
  for (int i = tid; i < MTILE * HD; i += NTHR) {
    const int r = i >> 8, cc = i & 255;
    As1[r * AROW + cc] = As0[r * AROW + 80 + cc];
  }
  __syncthreads();

#pragma unroll 1
  for (int L = 0; L < NL; ++L) {
    const _Float16* in = (L & 1) ? As0 : As1;
    _Float16*       ob = (L & 1) ? As1 : As0;
    const _Float16* wl = wsW + WS_MLP + (size_t)L * (128 * 512);
    float bcol[2];
    bcol[0] = mlpb[L * HD + w * 32 + l15];
    bcol[1] = mlpb[L * HD + w * 32 + 16 + l15];

    f4 acc[2];
    acc[0] = f4{0.f, 0.f, 0.f, 0.f};
    acc[1] = f4{0.f, 0.f, 0.f, 0.f};
#pragma unroll
    for (int kt = 0; kt < 8; ++kt) {
      const h8 a0 = *(const h8*)&in[l15 * AROW + kt * 32 + lq * 8];
#pragma unroll
      for (int cb = 0; cb < 2; ++cb) {
        const h8 bf = *(const h8*)&wl[(size_t)((w * 2 + cb) * 8 + kt) * 512 + l * 8];
        acc[cb] = __builtin_amdgcn_mfma_f32_16x16x32_f16(a0, bf, acc[cb], 0, 0, 0);
      }
    }
#pragma unroll
    for (int cb = 0; cb < 2; ++cb)
#pragma unroll
      for (int r = 0; r < 4; ++r) {
        const float z = acc[cb][r] + bcol[cb];
        const float ez = __builtin_amdgcn_exp2f(z * -1.44269504088896f);
        ob[(lq * 4 + r) * AROW + w * 32 + cb * 16 + l15] =
            (_Float16)(z * __builtin_amdgcn_rcpf(1.f + ez));
      }
    __syncthreads();
  }

  // Output layer: final activations in As0 (NL=5 odd). N=64 -> waves 0..3.
  if (w < 4) {
    const _Float16* wo = wsW + WS_WOUT;
    const float bo = bout[w * 16 + l15];
    f4 acc0 = f4{0.f, 0.f, 0.f, 0.f};
#pragma unroll
    for (int kt = 0; kt < 8; ++kt) {
      const h8 a0 = *(const h8*)&As0[l15 * AROW + kt * 32 + lq * 8];
      const h8 bf = *(const h8*)&wo[(size_t)(w * 8 + kt) * 512 + l * 8];
      acc0 = __builtin_amdgcn_mfma_f32_16x16x32_f16(a0, bf, acc0, 0, 0, 0);
    }
#pragma unroll
    for (int r = 0; r < 4; ++r)
      out[(size_t)(rbase + lq * 4 + r) * DOUT + w * 16 + l15] = acc0[r] + bo;
  }
}

// ------------------------------- launcher ----------------------------------
extern "C" void kernel_launch(void* const* d_in, const int* in_sizes, int n_in,
                              void* d_out, int out_size, void* d_ws, size_t ws_size,
                              hipStream_t stream)
{
  const float* traj = (const float*)d_in[0];
  const float* acts = (const float*)d_in[1];
  const float* Wi   = (const float*)d_in[2];
  const float* Wh   = (const float*)d_in[3];
  const float* bh   = (const float*)d_in[4];
  const float* mlpW = (const float*)d_in[5];
  const float* mlpb = (const float*)d_in[6];
  const float* Wout = (const float*)d_in[7];
  const float* bout = (const float*)d_in[8];
  _Float16* wsW = (_Float16*)d_ws;   // needs 1,409,024 bytes of workspace

  (void)hipFuncSetAttribute((const void*)lstm_kernel,
                            hipFuncAttributeMaxDynamicSharedMemorySize, LDS_BYTES);

  repack_kernel<<<344, 256, 0, stream>>>(Wi, Wh, mlpW, Wout, wsW);
  lstm_kernel<<<NWG, NTHR, LDS_BYTES, stream>>>(traj, acts, bh, mlpb, bout, wsW, (float*)d_out);
}